// Round 1
// baseline (984.293 us; speedup 1.0000x reference)
//
#include <hip/hip_runtime.h>
#include <stdint.h>

#define BB 8
#define SS 1024
#define EE 1024
#define HH 16
#define HDD 64

typedef unsigned short u16_t;
typedef __attribute__((ext_vector_type(8))) short short8;
typedef __attribute__((ext_vector_type(4))) float f32x4;

__device__ __forceinline__ u16_t f2bf(float f){
    union { float f; uint32_t u; } v; v.f = f;
    return (u16_t)((v.u + 0x7fffu + ((v.u >> 16) & 1u)) >> 16);
}

__device__ __forceinline__ void gload_lds16(const void* g, void* l){
    __builtin_amdgcn_global_load_lds((const __attribute__((address_space(1))) unsigned int*)g,
                                     (__attribute__((address_space(3))) unsigned int*)l, 16, 0, 0);
}

#define MFMA16(a,b,c) __builtin_amdgcn_mfma_f32_16x16x32_bf16(a,b,c,0,0,0)

union U8 { short8 v; u16_t u[8]; };

// ---------------- f32 -> bf16 convert (vectorized, grid-stride) ----------------
__global__ __launch_bounds__(256) void cvt_f32_bf16(const float* __restrict__ in,
                                                    u16_t* __restrict__ out, int n8){
    int i = blockIdx.x * blockDim.x + threadIdx.x;
    int stride = gridDim.x * blockDim.x;
    for (; i < n8; i += stride){
        const float4* p = (const float4*)(in + (size_t)i * 8);
        float4 a = p[0], b = p[1];
        U8 o;
        o.u[0]=f2bf(a.x); o.u[1]=f2bf(a.y); o.u[2]=f2bf(a.z); o.u[3]=f2bf(a.w);
        o.u[4]=f2bf(b.x); o.u[5]=f2bf(b.y); o.u[6]=f2bf(b.z); o.u[7]=f2bf(b.w);
        *(short8*)(out + (size_t)i * 8) = o.v;
    }
}

// ---------------- C[M,N] = A[M,K] * B[N,K]^T + bias ; 128x128 tile, BK=32 ----------------
template<bool OUTF32>
__global__ __launch_bounds__(256) void gemm_bt(const u16_t* __restrict__ A,
                                               const u16_t* __restrict__ Bw,
                                               const float* __restrict__ bias,
                                               void* __restrict__ Cout,
                                               int M, int N, int K)
{
    __shared__ u16_t sA[128 * 32];
    __shared__ u16_t sB[128 * 32];
    const int tid = threadIdx.x;
    const int wave = tid >> 6, lane = tid & 63;
    const int m0 = blockIdx.y * 128, n0 = blockIdx.x * 128;
    const int wm = (wave >> 1) * 64, wn = (wave & 1) * 64;

    f32x4 acc[4][4] = {};

    for (int k0 = 0; k0 < K; k0 += 32){
        // stage A,B tiles: 8192 B each = 8 wave-issues; layout [row][32] linear
        #pragma unroll
        for (int i = 0; i < 2; i++){
            int s   = (wave * 2 + i) * 64 + lane;
            int row = s >> 2, cb = (s & 3) * 8;
            gload_lds16(A  + (size_t)(m0 + row) * K + k0 + cb, (void*)(sA + (wave * 2 + i) * 512));
            gload_lds16(Bw + (size_t)(n0 + row) * K + k0 + cb, (void*)(sB + (wave * 2 + i) * 512));
        }
        __syncthreads();

        short8 aF[4], bF[4];
        #pragma unroll
        for (int m = 0; m < 4; m++)
            aF[m] = *(const short8*)(sA + (wm + m * 16 + (lane & 15)) * 32 + (lane >> 4) * 8);
        #pragma unroll
        for (int n = 0; n < 4; n++)
            bF[n] = *(const short8*)(sB + (wn + n * 16 + (lane & 15)) * 32 + (lane >> 4) * 8);
        #pragma unroll
        for (int m = 0; m < 4; m++)
            #pragma unroll
            for (int n = 0; n < 4; n++)
                acc[m][n] = MFMA16(aF[m], bF[n], acc[m][n]);
        __syncthreads();
    }

    #pragma unroll
    for (int m = 0; m < 4; m++){
        #pragma unroll
        for (int n = 0; n < 4; n++){
            int col = n0 + wn + n * 16 + (lane & 15);
            float bv = bias[col];
            #pragma unroll
            for (int j = 0; j < 4; j++){
                int row = m0 + wm + m * 16 + (lane >> 4) * 4 + j;
                float v = acc[m][n][j] + bv;
                if (OUTF32) ((float*)Cout)[(size_t)row * N + col] = v;
                else        ((u16_t*)Cout)[(size_t)row * N + col] = f2bf(v);
            }
        }
    }
}

// ---------------- attention pass 1: row sums of exp(logits) ----------------
// grid: (S/64, H, B), 256 threads (4 waves); wave w owns rows w*16..w*16+15 of the Q-tile
__global__ __launch_bounds__(256) void attn_rowsum(const u16_t* __restrict__ Qp,
                                                   const u16_t* __restrict__ Kp,
                                                   const int* __restrict__ mask,
                                                   float* __restrict__ rowsum)
{
    __shared__ u16_t sQ[64 * 64];
    __shared__ u16_t sK[64 * 64];
    const int b = blockIdx.z, h = blockIdx.y, i0 = blockIdx.x * 64;
    const int tid = threadIdx.x, wave = tid >> 6, lane = tid & 63;

    {   // stage Q tile [64 rows][64 dims]
        int r = tid >> 2, cb = (tid & 3) * 16;
        const u16_t* src = Qp + (size_t)(b * SS + i0 + r) * EE + h * HDD + cb;
        *(short8*)(sQ + r * 64 + cb)     = *(const short8*)(src);
        *(short8*)(sQ + r * 64 + cb + 8) = *(const short8*)(src + 8);
    }
    __syncthreads();
    short8 aF0 = *(const short8*)(sQ + (wave * 16 + (lane & 15)) * 64      + (lane >> 4) * 8);
    short8 aF1 = *(const short8*)(sQ + (wave * 16 + (lane & 15)) * 64 + 32 + (lane >> 4) * 8);

    float s_run[4] = {0.f, 0.f, 0.f, 0.f};
    const int ib = i0 + wave * 16 + (lane >> 4) * 4;

    for (int j0 = 0; j0 < SS; j0 += 64){
        __syncthreads();
        {   // stage K tile [64 rows(j)][64 dims]
            int r = tid >> 2, cb = (tid & 3) * 16;
            const u16_t* src = Kp + (size_t)(b * SS + j0 + r) * EE + h * HDD + cb;
            *(short8*)(sK + r * 64 + cb)     = *(const short8*)(src);
            *(short8*)(sK + r * 64 + cb + 8) = *(const short8*)(src + 8);
        }
        __syncthreads();
        #pragma unroll
        for (int n = 0; n < 4; n++){
            f32x4 acc = {};
            short8 bF = *(const short8*)(sK + (n * 16 + (lane & 15)) * 64      + (lane >> 4) * 8);
            acc = MFMA16(aF0, bF, acc);
            bF        = *(const short8*)(sK + (n * 16 + (lane & 15)) * 64 + 32 + (lane >> 4) * 8);
            acc = MFMA16(aF1, bF, acc);
            int j = j0 + n * 16 + (lane & 15);
            #pragma unroll
            for (int r = 0; r < 4; r++){
                float l = acc[r] * 0.125f + (float)mask[((size_t)b * SS + ib + r) * SS + j] * (-1e9f);
                s_run[r] += __expf(l);
            }
        }
    }
    #pragma unroll
    for (int r = 0; r < 4; r++){
        float v = s_run[r];
        v += __shfl_xor(v, 1); v += __shfl_xor(v, 2); v += __shfl_xor(v, 4); v += __shfl_xor(v, 8);
        s_run[r] = v;
    }
    if ((lane & 15) == 0){
        float* dst = rowsum + ((size_t)b * HH + h) * SS + ib;
        dst[0] = s_run[0]; dst[1] = s_run[1]; dst[2] = s_run[2]; dst[3] = s_run[3];
    }
}

// ---------------- attention pass 2: attn = exp(l)/sum + adjoin -> d_out ----------------
__global__ __launch_bounds__(256) void attn_write(const u16_t* __restrict__ Qp,
                                                  const u16_t* __restrict__ Kp,
                                                  const int* __restrict__ mask,
                                                  const float* __restrict__ adjoin,
                                                  const float* __restrict__ rowsum,
                                                  float* __restrict__ attn)
{
    __shared__ u16_t sQ[64 * 64];
    __shared__ u16_t sK[64 * 64];
    const int b = blockIdx.z, h = blockIdx.y, i0 = blockIdx.x * 64;
    const int tid = threadIdx.x, wave = tid >> 6, lane = tid & 63;

    {
        int r = tid >> 2, cb = (tid & 3) * 16;
        const u16_t* src = Qp + (size_t)(b * SS + i0 + r) * EE + h * HDD + cb;
        *(short8*)(sQ + r * 64 + cb)     = *(const short8*)(src);
        *(short8*)(sQ + r * 64 + cb + 8) = *(const short8*)(src + 8);
    }
    __syncthreads();
    short8 aF0 = *(const short8*)(sQ + (wave * 16 + (lane & 15)) * 64      + (lane >> 4) * 8);
    short8 aF1 = *(const short8*)(sQ + (wave * 16 + (lane & 15)) * 64 + 32 + (lane >> 4) * 8);

    const int ib = i0 + wave * 16 + (lane >> 4) * 4;
    float inv[4];
    #pragma unroll
    for (int r = 0; r < 4; r++)
        inv[r] = 1.0f / rowsum[((size_t)b * HH + h) * SS + ib + r];

    for (int j0 = 0; j0 < SS; j0 += 64){
        __syncthreads();
        {
            int r = tid >> 2, cb = (tid & 3) * 16;
            const u16_t* src = Kp + (size_t)(b * SS + j0 + r) * EE + h * HDD + cb;
            *(short8*)(sK + r * 64 + cb)     = *(const short8*)(src);
            *(short8*)(sK + r * 64 + cb + 8) = *(const short8*)(src + 8);
        }
        __syncthreads();
        #pragma unroll
        for (int n = 0; n < 4; n++){
            f32x4 acc = {};
            short8 bF = *(const short8*)(sK + (n * 16 + (lane & 15)) * 64      + (lane >> 4) * 8);
            acc = MFMA16(aF0, bF, acc);
            bF        = *(const short8*)(sK + (n * 16 + (lane & 15)) * 64 + 32 + (lane >> 4) * 8);
            acc = MFMA16(aF1, bF, acc);
            int j = j0 + n * 16 + (lane & 15);
            #pragma unroll
            for (int r = 0; r < 4; r++){
                size_t mrow = ((size_t)b * SS + ib + r) * SS + j;
                float l = acc[r] * 0.125f + (float)mask[mrow] * (-1e9f);
                float p = __expf(l) * inv[r] + adjoin[mrow];
                attn[(((size_t)b * HH + h) * SS + ib + r) * SS + j] = p;
            }
        }
    }
}

// ---------------- PV: X[b,i,h*64+d] = sum_j attn[b,h,i,j] * Vp[b,j,h*64+d] ----------------
// grid: (S/64, H, B), 256 threads; wave w owns output cols w*16..w*16+15
__global__ __launch_bounds__(256) void attn_pv(const float* __restrict__ attn,
                                               const u16_t* __restrict__ Vp,
                                               u16_t* __restrict__ X)
{
    __shared__ u16_t sAt[64 * 64];   // attn tile (bf16) [row i][k j]
    __shared__ u16_t sV[64 * 64];    // V tile [k j][col d]
    const int b = blockIdx.z, h = blockIdx.y, m0 = blockIdx.x * 64;
    const int tid = threadIdx.x, wave = tid >> 6, lane = tid & 63;

    f32x4 acc[4] = {};

    for (int j0 = 0; j0 < SS; j0 += 64){
        __syncthreads();
        {   // stage attn tile: 64x64 f32 -> bf16
            int r = tid >> 2, cb = (tid & 3) * 16;
            const float* asrc = attn + (((size_t)b * HH + h) * SS + m0 + r) * SS + j0 + cb;
            const float4* af = (const float4*)asrc;
            float4 f0 = af[0], f1 = af[1], f2 = af[2], f3 = af[3];
            U8 o0, o1;
            o0.u[0]=f2bf(f0.x); o0.u[1]=f2bf(f0.y); o0.u[2]=f2bf(f0.z); o0.u[3]=f2bf(f0.w);
            o0.u[4]=f2bf(f1.x); o0.u[5]=f2bf(f1.y); o0.u[6]=f2bf(f1.z); o0.u[7]=f2bf(f1.w);
            o1.u[0]=f2bf(f2.x); o1.u[1]=f2bf(f2.y); o1.u[2]=f2bf(f2.z); o1.u[3]=f2bf(f2.w);
            o1.u[4]=f2bf(f3.x); o1.u[5]=f2bf(f3.y); o1.u[6]=f2bf(f3.z); o1.u[7]=f2bf(f3.w);
            *(short8*)(sAt + r * 64 + cb)     = o0.v;
            *(short8*)(sAt + r * 64 + cb + 8) = o1.v;
            // stage V tile: rows j, cols d (bf16 direct)
            const u16_t* vsrc = Vp + (size_t)(b * SS + j0 + r) * EE + h * HDD + cb;
            *(short8*)(sV + r * 64 + cb)     = *(const short8*)(vsrc);
            *(short8*)(sV + r * 64 + cb + 8) = *(const short8*)(vsrc + 8);
        }
        __syncthreads();
        #pragma unroll
        for (int ks = 0; ks < 2; ks++){
            U8 bf;
            int colb = wave * 16 + (lane & 15);
            int kb = ks * 32 + (lane >> 4) * 8;
            #pragma unroll
            for (int jj = 0; jj < 8; jj++) bf.u[jj] = sV[(kb + jj) * 64 + colb];
            #pragma unroll
            for (int m = 0; m < 4; m++){
                short8 aF = *(const short8*)(sAt + (m * 16 + (lane & 15)) * 64 + ks * 32 + (lane >> 4) * 8);
                acc[m] = MFMA16(aF, bf.v, acc[m]);
            }
        }
    }

    #pragma unroll
    for (int m = 0; m < 4; m++){
        #pragma unroll
        for (int j = 0; j < 4; j++){
            int row = m0 + m * 16 + (lane >> 4) * 4 + j;
            int col = h * HDD + wave * 16 + (lane & 15);
            X[(size_t)(b * SS + row) * EE + col] = f2bf(acc[m][j]);
        }
    }
}

extern "C" void kernel_launch(void* const* d_in, const int* in_sizes, int n_in,
                              void* d_out, int out_size, void* d_ws, size_t ws_size,
                              hipStream_t stream)
{
    const float* query  = (const float*)d_in[0];
    const float* key    = (const float*)d_in[1];
    const float* value  = (const float*)d_in[2];
    const int*   mask   = (const int*)  d_in[3];
    const float* adjoin = (const float*)d_in[4];
    const float* Wq = (const float*)d_in[5];
    const float* bq = (const float*)d_in[6];
    const float* Wk = (const float*)d_in[7];
    const float* bk = (const float*)d_in[8];
    const float* Wv = (const float*)d_in[9];
    const float* bv = (const float*)d_in[10];
    const float* Wo = (const float*)d_in[11];
    const float* bo = (const float*)d_in[12];

    float* out  = (float*)d_out;
    float* attn = out + (size_t)BB * SS * EE;

    const size_t nBSE = (size_t)BB * SS * EE;   // 8388608
    const size_t nEE  = (size_t)EE * EE;        // 1048576

    u16_t* p  = (u16_t*)d_ws;
    u16_t* qb  = p; p += nBSE;
    u16_t* kb  = p; p += nBSE;
    u16_t* vb  = p; p += nBSE;
    u16_t* Qp  = p; p += nBSE;
    u16_t* Kp  = p; p += nBSE;
    u16_t* Vp  = p; p += nBSE;
    u16_t* Xa  = p; p += nBSE;
    u16_t* Wqb = p; p += nEE;
    u16_t* Wkb = p; p += nEE;
    u16_t* Wvb = p; p += nEE;
    u16_t* Wob = p; p += nEE;
    float* rowsum = (float*)p;   // B*H*S floats

    cvt_f32_bf16<<<1024, 256, 0, stream>>>(query, qb, (int)(nBSE / 8));
    cvt_f32_bf16<<<1024, 256, 0, stream>>>(key,   kb, (int)(nBSE / 8));
    cvt_f32_bf16<<<1024, 256, 0, stream>>>(value, vb, (int)(nBSE / 8));
    cvt_f32_bf16<<<256,  256, 0, stream>>>(Wq, Wqb, (int)(nEE / 8));
    cvt_f32_bf16<<<256,  256, 0, stream>>>(Wk, Wkb, (int)(nEE / 8));
    cvt_f32_bf16<<<256,  256, 0, stream>>>(Wv, Wvb, (int)(nEE / 8));
    cvt_f32_bf16<<<256,  256, 0, stream>>>(Wo, Wob, (int)(nEE / 8));

    dim3 gProj(EE / 128, (BB * SS) / 128);   // (8, 64)
    gemm_bt<false><<<gProj, 256, 0, stream>>>(qb, Wqb, bq, (void*)Qp, BB * SS, EE, EE);
    gemm_bt<false><<<gProj, 256, 0, stream>>>(kb, Wkb, bk, (void*)Kp, BB * SS, EE, EE);
    gemm_bt<false><<<gProj, 256, 0, stream>>>(vb, Wvb, bv, (void*)Vp, BB * SS, EE, EE);

    dim3 gAttn(SS / 64, HH, BB);             // (16, 16, 8)
    attn_rowsum<<<gAttn, 256, 0, stream>>>(Qp, Kp, mask, rowsum);
    attn_write <<<gAttn, 256, 0, stream>>>(Qp, Kp, mask, adjoin, rowsum, attn);
    attn_pv    <<<gAttn, 256, 0, stream>>>(attn, Vp, Xa);

    gemm_bt<true><<<gProj, 256, 0, stream>>>(Xa, Wob, bo, (void*)out, BB * SS, EE, EE);
}

// Round 2
// 602.657 us; speedup vs baseline: 1.6333x; 1.6333x over previous
//
#include <hip/hip_runtime.h>
#include <stdint.h>

#define BB 8
#define SS 1024
#define EE 1024
#define HH 16
#define HDD 64

typedef unsigned short u16_t;
typedef __attribute__((ext_vector_type(8))) short short8;
typedef __attribute__((ext_vector_type(4))) float f32x4;

__device__ __forceinline__ u16_t f2bf(float f){
    union { float f; uint32_t u; } v; v.f = f;
    return (u16_t)((v.u + 0x7fffu + ((v.u >> 16) & 1u)) >> 16);
}

__device__ __forceinline__ void gload_lds16(const void* g, void* l){
    __builtin_amdgcn_global_load_lds((const __attribute__((address_space(1))) unsigned int*)g,
                                     (__attribute__((address_space(3))) unsigned int*)l, 16, 0, 0);
}

#define MFMA16(a,b,c) __builtin_amdgcn_mfma_f32_16x16x32_bf16(a,b,c,0,0,0)

union U8 { short8 v; u16_t u[8]; };

// ---------------- f32 -> bf16 convert (vectorized, grid-stride) ----------------
__global__ __launch_bounds__(256) void cvt_f32_bf16(const float* __restrict__ in,
                                                    u16_t* __restrict__ out, int n8){
    int i = blockIdx.x * blockDim.x + threadIdx.x;
    int stride = gridDim.x * blockDim.x;
    for (; i < n8; i += stride){
        const float4* p = (const float4*)(in + (size_t)i * 8);
        float4 a = p[0], b = p[1];
        U8 o;
        o.u[0]=f2bf(a.x); o.u[1]=f2bf(a.y); o.u[2]=f2bf(a.z); o.u[3]=f2bf(a.w);
        o.u[4]=f2bf(b.x); o.u[5]=f2bf(b.y); o.u[6]=f2bf(b.z); o.u[7]=f2bf(b.w);
        *(short8*)(out + (size_t)i * 8) = o.v;
    }
}

// ---------------- C[M,N] = A[M,K] * B[N,K]^T + bias ; 128x128 tile, BK=32 ----------------
template<bool OUTF32>
__global__ __launch_bounds__(256) void gemm_bt(const u16_t* __restrict__ A,
                                               const u16_t* __restrict__ Bw,
                                               const float* __restrict__ bias,
                                               void* __restrict__ Cout,
                                               int M, int N, int K)
{
    __shared__ u16_t sA[128 * 32];
    __shared__ u16_t sB[128 * 32];
    const int tid = threadIdx.x;
    const int wave = tid >> 6, lane = tid & 63;
    const int m0 = blockIdx.y * 128, n0 = blockIdx.x * 128;
    const int wm = (wave >> 1) * 64, wn = (wave & 1) * 64;

    f32x4 acc[4][4] = {};

    for (int k0 = 0; k0 < K; k0 += 32){
        #pragma unroll
        for (int i = 0; i < 2; i++){
            int s   = (wave * 2 + i) * 64 + lane;
            int row = s >> 2, cb = (s & 3) * 8;
            gload_lds16(A  + (size_t)(m0 + row) * K + k0 + cb, (void*)(sA + (wave * 2 + i) * 512));
            gload_lds16(Bw + (size_t)(n0 + row) * K + k0 + cb, (void*)(sB + (wave * 2 + i) * 512));
        }
        __syncthreads();

        short8 aF[4], bF[4];
        #pragma unroll
        for (int m = 0; m < 4; m++)
            aF[m] = *(const short8*)(sA + (wm + m * 16 + (lane & 15)) * 32 + (lane >> 4) * 8);
        #pragma unroll
        for (int n = 0; n < 4; n++)
            bF[n] = *(const short8*)(sB + (wn + n * 16 + (lane & 15)) * 32 + (lane >> 4) * 8);
        #pragma unroll
        for (int m = 0; m < 4; m++)
            #pragma unroll
            for (int n = 0; n < 4; n++)
                acc[m][n] = MFMA16(aF[m], bF[n], acc[m][n]);
        __syncthreads();
    }

    #pragma unroll
    for (int m = 0; m < 4; m++){
        #pragma unroll
        for (int n = 0; n < 4; n++){
            int col = n0 + wn + n * 16 + (lane & 15);
            float bv = bias[col];
            #pragma unroll
            for (int j = 0; j < 4; j++){
                int row = m0 + wm + m * 16 + (lane >> 4) * 4 + j;
                float v = acc[m][n][j] + bv;
                if (OUTF32) ((float*)Cout)[(size_t)row * N + col] = v;
                else        ((u16_t*)Cout)[(size_t)row * N + col] = f2bf(v);
            }
        }
    }
}

// ---------------- fused attention: QK^T -> softmax -> +adjoin -> attn out + PV ----------------
// grid: (S/64, H, B), 256 threads (4 waves); wave w owns Q rows [w*16, w*16+16)
__global__ __launch_bounds__(256) void attn_fused(const u16_t* __restrict__ Qp,
                                                  const u16_t* __restrict__ Kp,
                                                  const u16_t* __restrict__ Vp,
                                                  const int* __restrict__ mask,
                                                  const float* __restrict__ adjoin,
                                                  float* __restrict__ attn,
                                                  u16_t* __restrict__ X)
{
    __shared__ u16_t sK[64 * 64];     // K tile, swizzled [row][128B], byte ^= (row&7)<<4
    __shared__ u16_t sV[64 * 64];     // V tile, linear [j][d]
    __shared__ u16_t sMB[64 * 68];    // mask bias bf16 (0 or 0xCE6E ~ -1e9), stride 68
    __shared__ u16_t sPB[64 * 64];    // attn tile bf16, swizzled
    __shared__ float sP[64 * 68];     // attn tile f32, stride 68; reused as Q staging at start

    const int b = blockIdx.z, h = blockIdx.y, i0 = blockIdx.x * 64;
    const int tid = threadIdx.x, wave = tid >> 6, lane = tid & 63;
    const int frow = lane & 15, fks = lane >> 4;

    // ---- stage Q tile (swizzled) into sP region, extract fragments
    u16_t* sQ = (u16_t*)sP;
    #pragma unroll
    for (int i = 0; i < 2; i++){
        int chunk = (wave * 2 + i) * 64 + lane;
        int row = chunk >> 3, slot = chunk & 7;
        gload_lds16(Qp + (size_t)(b * SS + i0 + row) * EE + h * HDD + (slot ^ (row & 7)) * 8,
                    (void*)(sQ + (wave * 2 + i) * 512));
    }
    __syncthreads();
    short8 aQ0, aQ1;
    {
        int row = wave * 16 + frow;
        aQ0 = *(const short8*)((const char*)sQ + row * 128 + ((fks * 16)      ^ ((row & 7) << 4)));
        aQ1 = *(const short8*)((const char*)sQ + row * 128 + ((64 + fks * 16) ^ ((row & 7) << 4)));
    }

    // ---- staging helpers
    auto stageK = [&](int j0){
        #pragma unroll
        for (int i = 0; i < 2; i++){
            int chunk = (wave * 2 + i) * 64 + lane;
            int row = chunk >> 3, slot = chunk & 7;
            gload_lds16(Kp + (size_t)(b * SS + j0 + row) * EE + h * HDD + (slot ^ (row & 7)) * 8,
                        (void*)(sK + (wave * 2 + i) * 512));
        }
    };
    auto stageV = [&](int j0){
        #pragma unroll
        for (int i = 0; i < 2; i++){
            int chunk = (wave * 2 + i) * 64 + lane;
            int row = chunk >> 3, slot = chunk & 7;
            gload_lds16(Vp + (size_t)(b * SS + j0 + row) * EE + h * HDD + slot * 8,
                        (void*)(sV + (wave * 2 + i) * 512));
        }
    };
    auto stageMB = [&](int j0){
        int r0 = tid >> 4, c = (tid & 15) * 4;
        #pragma unroll
        for (int rr = 0; rr < 4; rr++){
            int r = r0 + rr * 16;
            const int4 m4 = *(const int4*)(mask + (size_t)(b * SS + i0 + r) * SS + j0 + c);
            uint32_t lo = (m4.x ? 0xCE6Eu : 0u) | ((m4.y ? 0xCE6Eu : 0u) << 16);
            uint32_t hi = (m4.z ? 0xCE6Eu : 0u) | ((m4.w ? 0xCE6Eu : 0u) << 16);
            *(uint2*)(sMB + r * 68 + c) = make_uint2(lo, hi);
        }
    };

    // ================= pass 1: rowsums of exp =================
    float s_run[4] = {0.f, 0.f, 0.f, 0.f};
    for (int j0 = 0; j0 < SS; j0 += 64){
        stageK(j0); stageMB(j0);
        __syncthreads();
        #pragma unroll
        for (int n = 0; n < 4; n++){
            int jrow = n * 16 + frow;
            f32x4 acc = {};
            short8 bF = *(const short8*)((const char*)sK + jrow * 128 + ((fks * 16)      ^ ((jrow & 7) << 4)));
            acc = MFMA16(aQ0, bF, acc);
            bF        = *(const short8*)((const char*)sK + jrow * 128 + ((64 + fks * 16) ^ ((jrow & 7) << 4)));
            acc = MFMA16(aQ1, bF, acc);
            #pragma unroll
            for (int r = 0; r < 4; r++){
                int irow = wave * 16 + fks * 4 + r;
                uint32_t mb = sMB[irow * 68 + n * 16 + frow];
                float bias = __uint_as_float(mb << 16);
                s_run[r] += __expf(acc[r] * 0.125f + bias);
            }
        }
        __syncthreads();
    }
    float inv[4];
    #pragma unroll
    for (int r = 0; r < 4; r++){
        float v = s_run[r];
        v += __shfl_xor(v, 1); v += __shfl_xor(v, 2); v += __shfl_xor(v, 4); v += __shfl_xor(v, 8);
        inv[r] = 1.0f / v;
    }

    // ================= pass 2: attn write + PV =================
    f32x4 accPV[4] = {};
    for (int j0 = 0; j0 < SS; j0 += 64){
        stageK(j0); stageV(j0); stageMB(j0);
        __syncthreads();
        // QK^T + exp -> sP (f32, stride 68)
        #pragma unroll
        for (int n = 0; n < 4; n++){
            int jrow = n * 16 + frow;
            f32x4 acc = {};
            short8 bF = *(const short8*)((const char*)sK + jrow * 128 + ((fks * 16)      ^ ((jrow & 7) << 4)));
            acc = MFMA16(aQ0, bF, acc);
            bF        = *(const short8*)((const char*)sK + jrow * 128 + ((64 + fks * 16) ^ ((jrow & 7) << 4)));
            acc = MFMA16(aQ1, bF, acc);
            #pragma unroll
            for (int r = 0; r < 4; r++){
                int irow = wave * 16 + fks * 4 + r;
                uint32_t mb = sMB[irow * 68 + n * 16 + frow];
                float bias = __uint_as_float(mb << 16);
                sP[irow * 68 + n * 16 + frow] = __expf(acc[r] * 0.125f + bias) * inv[r];
            }
        }
        __syncthreads();
        // vectorized: + adjoin, coalesced float4 attn store, bf16 tile to sPB
        {
            int rb = tid >> 4, c4 = tid & 15;
            #pragma unroll
            for (int rr = 0; rr < 4; rr++){
                int row = rb + rr * 16;
                f32x4 pv = *(const f32x4*)(sP + row * 68 + c4 * 4);
                const float4 adj = *(const float4*)(adjoin + (size_t)(b * SS + i0 + row) * SS + j0 + c4 * 4);
                f32x4 att;
                att[0] = pv[0] + adj.x; att[1] = pv[1] + adj.y;
                att[2] = pv[2] + adj.z; att[3] = pv[3] + adj.w;
                *(f32x4*)(attn + ((size_t)(b * HH + h) * SS + i0 + row) * SS + j0 + c4 * 4) = att;
                uint32_t lo = (uint32_t)f2bf(att[0]) | ((uint32_t)f2bf(att[1]) << 16);
                uint32_t hi = (uint32_t)f2bf(att[2]) | ((uint32_t)f2bf(att[3]) << 16);
                *(uint2*)((char*)sPB + row * 128 + ((c4 * 8) ^ ((row & 7) << 4))) = make_uint2(lo, hi);
            }
        }
        __syncthreads();
        // PV MFMA: accPV[n] += P(16 x 64j) * V(64j x 16d)
        {
            int prow = wave * 16 + frow;
            short8 aP0 = *(const short8*)((const char*)sPB + prow * 128 + ((fks * 16)      ^ ((prow & 7) << 4)));
            short8 aP1 = *(const short8*)((const char*)sPB + prow * 128 + ((64 + fks * 16) ^ ((prow & 7) << 4)));
            #pragma unroll
            for (int n = 0; n < 4; n++){
                U8 bv0, bv1;
                int d = n * 16 + frow;
                #pragma unroll
                for (int e = 0; e < 8; e++){
                    bv0.u[e] = sV[(fks * 8 + e) * 64 + d];
                    bv1.u[e] = sV[(32 + fks * 8 + e) * 64 + d];
                }
                accPV[n] = MFMA16(aP0, bv0.v, accPV[n]);
                accPV[n] = MFMA16(aP1, bv1.v, accPV[n]);
            }
        }
        __syncthreads();
    }

    // ---- X write (bf16): rows = wave's Q rows, cols = h*64 + d
    #pragma unroll
    for (int n = 0; n < 4; n++){
        #pragma unroll
        for (int j = 0; j < 4; j++){
            int row = i0 + wave * 16 + fks * 4 + j;
            int col = h * HDD + n * 16 + frow;
            X[(size_t)(b * SS + row) * EE + col] = f2bf(accPV[n][j]);
        }
    }
}

extern "C" void kernel_launch(void* const* d_in, const int* in_sizes, int n_in,
                              void* d_out, int out_size, void* d_ws, size_t ws_size,
                              hipStream_t stream)
{
    const float* query  = (const float*)d_in[0];
    const float* key    = (const float*)d_in[1];
    const float* value  = (const float*)d_in[2];
    const int*   mask   = (const int*)  d_in[3];
    const float* adjoin = (const float*)d_in[4];
    const float* Wq = (const float*)d_in[5];
    const float* bq = (const float*)d_in[6];
    const float* Wk = (const float*)d_in[7];
    const float* bk = (const float*)d_in[8];
    const float* Wv = (const float*)d_in[9];
    const float* bv = (const float*)d_in[10];
    const float* Wo = (const float*)d_in[11];
    const float* bo = (const float*)d_in[12];

    float* out  = (float*)d_out;
    float* attn = out + (size_t)BB * SS * EE;

    const size_t nBSE = (size_t)BB * SS * EE;   // 8388608
    const size_t nEE  = (size_t)EE * EE;        // 1048576

    u16_t* p  = (u16_t*)d_ws;
    u16_t* qb  = p; p += nBSE;
    u16_t* kb  = p; p += nBSE;
    u16_t* vb  = p; p += nBSE;
    u16_t* Qp  = p; p += nBSE;
    u16_t* Kp  = p; p += nBSE;
    u16_t* Vp  = p; p += nBSE;
    u16_t* Xa  = p; p += nBSE;
    u16_t* Wqb = p; p += nEE;
    u16_t* Wkb = p; p += nEE;
    u16_t* Wvb = p; p += nEE;
    u16_t* Wob = p; p += nEE;

    cvt_f32_bf16<<<1024, 256, 0, stream>>>(query, qb, (int)(nBSE / 8));
    cvt_f32_bf16<<<1024, 256, 0, stream>>>(key,   kb, (int)(nBSE / 8));
    cvt_f32_bf16<<<1024, 256, 0, stream>>>(value, vb, (int)(nBSE / 8));
    cvt_f32_bf16<<<256,  256, 0, stream>>>(Wq, Wqb, (int)(nEE / 8));
    cvt_f32_bf16<<<256,  256, 0, stream>>>(Wk, Wkb, (int)(nEE / 8));
    cvt_f32_bf16<<<256,  256, 0, stream>>>(Wv, Wvb, (int)(nEE / 8));
    cvt_f32_bf16<<<256,  256, 0, stream>>>(Wo, Wob, (int)(nEE / 8));

    dim3 gProj(EE / 128, (BB * SS) / 128);   // (8, 64)
    gemm_bt<false><<<gProj, 256, 0, stream>>>(qb, Wqb, bq, (void*)Qp, BB * SS, EE, EE);
    gemm_bt<false><<<gProj, 256, 0, stream>>>(kb, Wkb, bk, (void*)Kp, BB * SS, EE, EE);
    gemm_bt<false><<<gProj, 256, 0, stream>>>(vb, Wvb, bv, (void*)Vp, BB * SS, EE, EE);

    dim3 gAttn(SS / 64, HH, BB);             // (16, 16, 8)
    attn_fused<<<gAttn, 256, 0, stream>>>(Qp, Kp, Vp, mask, adjoin, attn, Xa);

    gemm_bt<true><<<gProj, 256, 0, stream>>>(Xa, Wob, bo, (void*)out, BB * SS, EE, EE);
}